// Round 11
// baseline (231.840 us; speedup 1.0000x reference)
//
#include <hip/hip_runtime.h>
#include <hip/hip_bf16.h>

#define NB 8
#define CIN 512
#define COUT 512
#define SDIM 512

typedef __attribute__((ext_vector_type(8))) short short8;
typedef __attribute__((ext_vector_type(4))) float f32x4;

static constexpr float CONV_SCALE = 0.014731391274719740f;  // 1/sqrt(512*9)
static constexpr float LIN_SCALE  = 0.044194173824159216f;  // 1/sqrt(512)

// ---- workspace layout (bytes) ----
static constexpr size_t OFF_S     = 0;                      // 16384
static constexpr size_t OFF_WSQ   = 16384;                  // 1048576
static constexpr size_t OFF_DEMOD = 1064960;                // 16384 (ends 1081344)
static constexpr size_t OFF_XP    = 1081344;                // 9469952
static constexpr size_t OFF_WP    = 10551296;               // 4718592
static constexpr size_t OFF_Y1    = 15269888;               // y1 bf16 padded: 34619392 B

// job table, long-K-first: ps0 [0,276) ps1 [276,540) ps2 [540,804) ps3 [804,1060)
static constexpr int NJOBS = 1060;

__device__ __forceinline__ int wpoff(int ps) {
  return ps == 0 ? 0 : ps == 1 ? 1048576 : ps == 2 ? 1572864 : 2097152;
}
// per-(co,b) plane stride (elements, even) and phase base (elements, even)
__device__ __forceinline__ constexpr int PSPAD(int ps) {
  return ps == 0 ? 1090 : ps == 3 ? 1024 : 1056;
}
__device__ __forceinline__ constexpr int PLB(int ps) {
  return ps == 0 ? 0 : ps == 1 ? 4464640 : ps == 2 ? 8790016 : 13115392;
}

__device__ __forceinline__ short f2bf(float f) {
  unsigned u = __builtin_bit_cast(unsigned, f);
  unsigned r = (u + 0x7fffu + ((u >> 16) & 1u)) >> 16;
  return (short)r;
}
__device__ __forceinline__ float bf2f(unsigned short u) {
  return __builtin_bit_cast(float, (unsigned)u << 16);
}

// ---- K_prep1: wprep (blocks 0..1023)  ||  style (blocks 1024..1151) ----
__global__ void k_prep1(const float* __restrict__ style, const float* __restrict__ mod_w,
                        const float* __restrict__ mod_b, float* __restrict__ s_out,
                        const float* __restrict__ w, short* __restrict__ wp,
                        float* __restrict__ wsq) {
  const int tid = threadIdx.x;
  if (blockIdx.x < 1024) {
    int idx = blockIdx.x * 256 + tid;  // (co,ci)
    int co = idx >> 9, ci = idx & 511;
    float wv[3][3];
    float sq = 0.f;
#pragma unroll
    for (int i = 0; i < 9; ++i) {
      float v = w[idx * 9 + i];
      wv[i / 3][i % 3] = v;
      sq += v * v;
    }
    wsq[idx] = sq * CONV_SCALE * CONV_SCALE;
#pragma unroll
    for (int wy = 0; wy < 3; ++wy)
#pragma unroll
      for (int wx = 0; wx < 3; ++wx) {
        int psy = (wy == 1) ? 1 : 0, psx = (wx == 1) ? 1 : 0;
        int u = psy ? 0 : (wy == 0 ? 1 : 0);
        int v = psx ? 0 : (wx == 0 ? 1 : 0);
        int ps = psy * 2 + psx;
        int tap = psy ? (psx ? 0 : v) : (psx ? u : u * 2 + v);
        int k = tap * 512 + ci;
        int elem = wpoff(ps) + ((k >> 6) * 512 + co) * 64 + (k & 63);
        wp[elem] = f2bf(wv[wy][wx] * CONV_SCALE);
      }
  } else {
    int wid = tid >> 6, lane = tid & 63;
    int ci = (blockIdx.x - 1024) * 4 + wid;
    float acc[NB] = {};
    for (int k = lane; k < SDIM; k += 64) {
      float wm = mod_w[ci * SDIM + k];
#pragma unroll
      for (int b = 0; b < NB; ++b) acc[b] += wm * style[b * SDIM + k];
    }
#pragma unroll
    for (int b = 0; b < NB; ++b) {
      float v = acc[b];
      for (int o = 32; o > 0; o >>= 1) v += __shfl_xor(v, o);
      if (lane == 0) s_out[b * CIN + ci] = v * LIN_SCALE + mod_b[ci];
    }
  }
}

// ---- K_prep2: xprep (0..1023) || demod (1024..1151) || xp border-zero (1152..1183) ----
__global__ void k_prep2(const float* __restrict__ wsq, const float* __restrict__ s,
                        float* __restrict__ demod,
                        const float* __restrict__ x, short* __restrict__ xp) {
  const int tid = threadIdx.x;
  if (blockIdx.x < 1024) {
    __shared__ float t[64][65];
    const int tx = tid & 63, ty = tid >> 6;
    int bx = blockIdx.x;
    int sp0 = (bx & 15) * 64, ci0 = ((bx >> 4) & 7) * 64, b = bx >> 7;
    for (int r = ty; r < 64; r += 4)
      t[r][tx] = x[(b * CIN + ci0 + r) * 1024 + sp0 + tx];
    __syncthreads();
    int ci = ci0 + tx;
    float sv = s[b * CIN + ci];
    for (int r = ty; r < 64; r += 4) {
      int sp = sp0 + r;
      int yy = sp >> 5, xx = sp & 31;
      xp[((b * 34 + yy + 1) * 34 + (xx + 1)) * 512 + ci] = f2bf(t[tx][r] * sv);
    }
  } else if (blockIdx.x < 1152) {
    int wid = tid >> 6, lane = tid & 63;
    int co = (blockIdx.x - 1024) * 4 + wid;
    float acc[NB] = {};
    for (int ci = lane; ci < CIN; ci += 64) {
      float wq = wsq[co * CIN + ci];
#pragma unroll
      for (int b = 0; b < NB; ++b) {
        float sv = s[b * CIN + ci];
        acc[b] += wq * sv * sv;
      }
    }
#pragma unroll
    for (int b = 0; b < NB; ++b) {
      float v = acc[b];
      for (int o = 32; o > 0; o >>= 1) v += __shfl_xor(v, o);
      if (lane == 0) demod[b * COUT + co] = rsqrtf(v + 1e-8f);
    }
  } else {
    // zero the 132 border cells (yy or xx in {0,33}) of xp[b]; 4 blocks per b
    int idx = blockIdx.x - 1152;     // 0..31
    int b = idx >> 2, part = idx & 3;
    unsigned* xpu = (unsigned*)xp;
    for (int k = 0; k < 33; ++k) {
      int c = part * 33 + k;
      int yy, xx;
      if (c < 34)       { yy = 0;            xx = c; }
      else if (c < 68)  { yy = 33;           xx = c - 34; }
      else if (c < 100) { yy = 1 + (c - 68); xx = 0; }
      else              { yy = 1 + (c - 100); xx = 33; }
      xpu[((((b * 34 + yy) * 34 + xx) * 512) >> 1) + tid] = 0u;
    }
  }
}

// ---- K5: no-LDS phase GEMMs. A (W) and B (X) fragments loaded per-lane
//      directly from L2-resident pre-tiled layouts. No barriers; TLP hides
//      latency (no LDS -> 3 blocks/CU, 12 waves/CU). ----
__global__ __launch_bounds__(256, 3) void k_gemm(const short* __restrict__ xp,
                                                 const short* __restrict__ wp,
                                                 short* __restrict__ y1) {
  const int tid = threadIdx.x;
  const int wid = tid >> 6, lane = tid & 63;
  const int hi = lane >> 4;                    // 16B col within 32-k half
  const int wm = (wid >> 1) * 64, wn = (wid & 1) * 64;

  // block -> job: XCD-grouped (bx%8 = XCD), phases interleaved mod 8
  const int bx = blockIdx.x;
  const int xcd = bx & 7, ii = bx >> 3;
  const int j = (((ii >> 2) << 3) + xcd) * 4 + (ii & 3);
  if (j >= NJOBS) return;

  int ps, base;
  if (j < 276)      { ps = 0; base = 0; }
  else if (j < 540) { ps = 1; base = 276; }
  else if (j < 804) { ps = 2; base = 540; }
  else              { ps = 3; base = 804; }
  const int r = j - base;
  const int nb = r >> 2, mb = r & 3;
  const int psy = ps >> 1, psx = ps & 1;
  const int Ny = 33 - psy, Nx = 33 - psx;
  const int NyNx = Ny * Nx;
  const int N = NB * NyNx;
  const int n0 = nb * 128, m0 = mb * 128;
  const int KT = (2 - psy) * (2 - psx) * 8;   // 32/16/16/8
  const short* wpb = wp + wpoff(ps);

  // A-fragment base pointers (per mf), advance by kt*32768 + ks*32
  const short* wbase[4];
#pragma unroll
  for (int mf = 0; mf < 4; ++mf)
    wbase[mf] = wpb + (m0 + wm + mf * 16 + (lane & 15)) * 64 + hi * 8;

  // B-fragment base pointers (per nf): decode n once
  const short* xbase[4];
#pragma unroll
  for (int nf = 0; nf < 4; ++nf) {
    int n = n0 + wn + nf * 16 + (lane & 15);
    if (n >= N) n = N - 1;
    int b = n / NyNx;
    int rem = n - b * NyNx;
    int a_y = rem / Nx;
    int a_x = rem - a_y * Nx;
    xbase[nf] = xp + ((b * 34 + a_y) * 34 + a_x) * 512 + hi * 8;
  }

  f32x4 acc[4][4] = {};

  for (int kt = 0; kt < KT; ++kt) {
    int tap = kt >> 3, ci0 = (kt & 7) << 6;
    int oy, ox;
    if (ps == 0)      { oy = tap >> 1; ox = tap & 1; }
    else if (ps == 1) { oy = tap;      ox = 1; }
    else if (ps == 2) { oy = 1;        ox = tap; }
    else              { oy = 1;        ox = 1; }
    const int goffX = (oy * 34 + ox) * 512 + ci0;
    const int goffW = kt * 32768;

#pragma unroll
    for (int ks = 0; ks < 2; ++ks) {
      short8 af[4], bf[4];
#pragma unroll
      for (int mf = 0; mf < 4; ++mf)
        af[mf] = *(const short8*)(wbase[mf] + goffW + ks * 32);
#pragma unroll
      for (int nf = 0; nf < 4; ++nf)
        bf[nf] = *(const short8*)(xbase[nf] + goffX + ks * 32);
#pragma unroll
      for (int mf = 0; mf < 4; ++mf)
#pragma unroll
        for (int nf = 0; nf < 4; ++nf)
          acc[mf][nf] = __builtin_amdgcn_mfma_f32_16x16x32_bf16(af[mf], bf[nf], acc[mf][nf], 0, 0, 0);
    }
  }

  // ---- epilogue: f32 acc -> bf16 y1, padded per-(co,b) planes ----
  const int psp = PSPAD(ps);
  const int plb = PLB(ps);
#pragma unroll
  for (int nf = 0; nf < 4; ++nf) {
    int n = n0 + wn + nf * 16 + (lane & 15);
    if (n < N) {
      int b = n / NyNx;
      int rem = n - b * NyNx;
      int nbase = plb + b * psp + rem;
#pragma unroll
      for (int mf = 0; mf < 4; ++mf) {
        int m = m0 + wm + mf * 16 + (lane >> 4) * 4;
#pragma unroll
        for (int rr = 0; rr < 4; ++rr)
          y1[nbase + (m + rr) * 8 * psp] = f2bf(acc[mf][nf][rr]);
      }
    }
  }
}

// ---- K6 v3: half-plane blur blocks. 2 blocks per (b,co): rows [h*32, h*32+32). ----
__global__ __launch_bounds__(256, 8) void k_blur(const short* __restrict__ y1,
                                                 const float* __restrict__ demod,
                                                 const float* __restrict__ bias,
                                                 float* __restrict__ out) {
  __shared__ float sin_[4][18 * 35];
  __shared__ float stmp[2][18][64];
  const int tid = threadIdx.x;
  const int bc = blockIdx.x & 4095;    // b*512 + co
  const int h = blockIdx.x >> 12;      // row half 0/1
  const int co = bc & 511, b = bc >> 9;
  const int m0v = h * 16;              // first padded-av row needed

  for (int i = tid; i < 4 * 18 * 35; i += 256) ((float*)sin_)[i] = 0.f;
  __syncthreads();

#pragma unroll
  for (int ps = 0; ps < 4; ++ps) {
    const int Nyv = 33 - (ps >> 1), Nxv = 33 - (ps & 1);
    const int total = Nyv * Nxv;
    const short* pl = y1 + PLB(ps) + (co * NB + b) * PSPAD(ps);
    for (int t2 = tid; t2 * 2 < total; t2 += 256) {
      int e0 = t2 * 2;
      unsigned pair = *(const unsigned*)&pl[e0];
      int av0 = e0 / Nxv, ah0 = e0 - av0 * Nxv;
      int lr0 = av0 + 1 - m0v;
      if (lr0 >= 0 && lr0 < 18)
        sin_[ps][lr0 * 35 + ah0 + 1] = bf2f((unsigned short)(pair & 0xffffu));
      int e1 = e0 + 1;
      if (e1 < total) {
        int av1 = e1 / Nxv, ah1 = e1 - av1 * Nxv;
        int lr1 = av1 + 1 - m0v;
        if (lr1 >= 0 && lr1 < 18)
          sin_[ps][lr1 * 35 + ah1 + 1] = bf2f((unsigned short)(pair >> 16));
      }
    }
  }
  __syncthreads();

  const int q = tid & 63;
  const int mx = q >> 1, fx = q & 1;
  int xp0, xi0, xp1, xi1, xp2, xi2, xp3, xi3;
  if (fx) { xp0 = 0; xi0 = mx + 1; xp1 = 1; xi1 = mx + 1; xp2 = 0; xi2 = mx + 2; xp3 = 1; xi3 = mx + 2; }
  else    { xp0 = 1; xi0 = mx;     xp1 = 0; xi1 = mx + 1; xp2 = 1; xi2 = mx + 1; xp3 = 0; xi3 = mx + 2; }

  for (int rt = tid >> 6; rt < 36; rt += 4) {  // rt = pv*18 + local row
    int pv = (rt >= 18) ? 1 : 0;
    int lr = rt - pv * 18;
    if (m0v + lr < 35) {
      float v = 0.25f * sin_[pv * 2 + xp0][lr * 35 + xi0]
              + 0.75f * sin_[pv * 2 + xp1][lr * 35 + xi1]
              + 0.75f * sin_[pv * 2 + xp2][lr * 35 + xi2]
              + 0.25f * sin_[pv * 2 + xp3][lr * 35 + xi3];
      stmp[pv][lr][q] = v;
    } else {
      stmp[pv][lr][q] = 0.f;
    }
  }
  __syncthreads();

  const float dm = demod[b * COUT + co], bs = bias[co];
  for (int pl_ = tid >> 6; pl_ < 32; pl_ += 4) {
    int myl = pl_ >> 1, fy = pl_ & 1;
    float v;
    if (fy) v = 0.25f * stmp[0][myl + 1][q] + 0.75f * stmp[1][myl + 1][q]
              + 0.75f * stmp[0][myl + 2][q] + 0.25f * stmp[1][myl + 2][q];
    else    v = 0.25f * stmp[1][myl][q]     + 0.75f * stmp[0][myl + 1][q]
              + 0.75f * stmp[1][myl + 1][q] + 0.25f * stmp[0][myl + 2][q];
    float val = dm * v + bs;
    int p = h * 32 + pl_;
    out[(bc * 64 + p) * 64 + q] = (val >= 0.f ? val : 0.2f * val) * 1.41421356237309515f;
  }
}

extern "C" void kernel_launch(void* const* d_in, const int* in_sizes, int n_in,
                              void* d_out, int out_size, void* d_ws, size_t ws_size,
                              hipStream_t stream) {
  const float* x      = (const float*)d_in[0];
  const float* style  = (const float*)d_in[1];
  const float* weight = (const float*)d_in[2];
  const float* mod_w  = (const float*)d_in[3];
  const float* mod_b  = (const float*)d_in[4];
  const float* bias   = (const float*)d_in[5];
  float* out = (float*)d_out;
  char* ws = (char*)d_ws;

  float* s     = (float*)(ws + OFF_S);
  float* wsq   = (float*)(ws + OFF_WSQ);
  float* demod = (float*)(ws + OFF_DEMOD);
  short* xp    = (short*)(ws + OFF_XP);
  short* wp    = (short*)(ws + OFF_WP);
  short* y1    = (short*)(ws + OFF_Y1);

  k_prep1<<<1152, 256, 0, stream>>>(style, mod_w, mod_b, s, weight, wp, wsq);
  k_prep2<<<1184, 256, 0, stream>>>(wsq, s, demod, x, xp);
  k_gemm<<<1088, 256, 0, stream>>>(xp, wp, y1);
  k_blur<<<8192, 256, 0, stream>>>(y1, demod, bias, out);
}

// Round 12
// 115.068 us; speedup vs baseline: 2.0148x; 2.0148x over previous
//
#include <hip/hip_runtime.h>
#include <hip/hip_bf16.h>

#define NB 8
#define CIN 512
#define COUT 512
#define SDIM 512

typedef __attribute__((ext_vector_type(8))) short short8;
typedef __attribute__((ext_vector_type(4))) float f32x4;

static constexpr float CONV_SCALE = 0.014731391274719740f;  // 1/sqrt(512*9)
static constexpr float LIN_SCALE  = 0.044194173824159216f;  // 1/sqrt(512)

// ---- workspace layout (bytes) ----
static constexpr size_t OFF_S     = 0;                      // 16384
static constexpr size_t OFF_WSQ   = 16384;                  // 1048576
static constexpr size_t OFF_DEMOD = 1064960;                // 16384 (ends 1081344)
static constexpr size_t OFF_XP    = 1081344;                // 9469952
static constexpr size_t OFF_WP    = 10551296;               // 4718592
static constexpr size_t OFF_Y1    = 15269888;               // y1 bf16 padded: 34619392 B

// job table, long-K-first: ps0 [0,276) ps1 [276,540) ps2 [540,804) ps3 [804,1060)
static constexpr int NJOBS = 1060;

__device__ __forceinline__ int wpoff(int ps) {
  return ps == 0 ? 0 : ps == 1 ? 1048576 : ps == 2 ? 1572864 : 2097152;
}
// per-(co,b) plane stride (elements, even) and phase base (elements, even)
__device__ __forceinline__ constexpr int PSPAD(int ps) {
  return ps == 0 ? 1090 : ps == 3 ? 1024 : 1056;
}
__device__ __forceinline__ constexpr int PLB(int ps) {
  return ps == 0 ? 0 : ps == 1 ? 4464640 : ps == 2 ? 8790016 : 13115392;
}

__device__ __forceinline__ short f2bf(float f) {
  unsigned u = __builtin_bit_cast(unsigned, f);
  unsigned r = (u + 0x7fffu + ((u >> 16) & 1u)) >> 16;
  return (short)r;
}
__device__ __forceinline__ float bf2f(unsigned short u) {
  return __builtin_bit_cast(float, (unsigned)u << 16);
}

__device__ __forceinline__ void load_lds16(const short* g, short* l) {
  __builtin_amdgcn_global_load_lds(
      (const __attribute__((address_space(1))) unsigned int*)g,
      (__attribute__((address_space(3))) unsigned int*)l, 16, 0, 0);
}

// ---- K_prep1: wprep (blocks 0..1023)  ||  style (blocks 1024..1151) ----
__global__ void k_prep1(const float* __restrict__ style, const float* __restrict__ mod_w,
                        const float* __restrict__ mod_b, float* __restrict__ s_out,
                        const float* __restrict__ w, short* __restrict__ wp,
                        float* __restrict__ wsq) {
  const int tid = threadIdx.x;
  if (blockIdx.x < 1024) {
    int idx = blockIdx.x * 256 + tid;  // (co,ci)
    int co = idx >> 9, ci = idx & 511;
    float wv[3][3];
    float sq = 0.f;
#pragma unroll
    for (int i = 0; i < 9; ++i) {
      float v = w[idx * 9 + i];
      wv[i / 3][i % 3] = v;
      sq += v * v;
    }
    wsq[idx] = sq * CONV_SCALE * CONV_SCALE;
#pragma unroll
    for (int wy = 0; wy < 3; ++wy)
#pragma unroll
      for (int wx = 0; wx < 3; ++wx) {
        int psy = (wy == 1) ? 1 : 0, psx = (wx == 1) ? 1 : 0;
        int u = psy ? 0 : (wy == 0 ? 1 : 0);
        int v = psx ? 0 : (wx == 0 ? 1 : 0);
        int ps = psy * 2 + psx;
        int tap = psy ? (psx ? 0 : v) : (psx ? u : u * 2 + v);
        int k = tap * 512 + ci;
        int elem = wpoff(ps) + ((k >> 6) * 512 + co) * 64 + (k & 63);
        wp[elem] = f2bf(wv[wy][wx] * CONV_SCALE);
      }
  } else {
    int wid = tid >> 6, lane = tid & 63;
    int ci = (blockIdx.x - 1024) * 4 + wid;
    float acc[NB] = {};
    for (int k = lane; k < SDIM; k += 64) {
      float wm = mod_w[ci * SDIM + k];
#pragma unroll
      for (int b = 0; b < NB; ++b) acc[b] += wm * style[b * SDIM + k];
    }
#pragma unroll
    for (int b = 0; b < NB; ++b) {
      float v = acc[b];
      for (int o = 32; o > 0; o >>= 1) v += __shfl_xor(v, o);
      if (lane == 0) s_out[b * CIN + ci] = v * LIN_SCALE + mod_b[ci];
    }
  }
}

// ---- K_prep2: xprep (0..1023) || demod (1024..1151) || xp border-zero (1152..1183) ----
__global__ void k_prep2(const float* __restrict__ wsq, const float* __restrict__ s,
                        float* __restrict__ demod,
                        const float* __restrict__ x, short* __restrict__ xp) {
  const int tid = threadIdx.x;
  if (blockIdx.x < 1024) {
    __shared__ float t[64][65];
    const int tx = tid & 63, ty = tid >> 6;
    int bx = blockIdx.x;
    int sp0 = (bx & 15) * 64, ci0 = ((bx >> 4) & 7) * 64, b = bx >> 7;
    for (int r = ty; r < 64; r += 4)
      t[r][tx] = x[(b * CIN + ci0 + r) * 1024 + sp0 + tx];
    __syncthreads();
    int ci = ci0 + tx;
    float sv = s[b * CIN + ci];
    for (int r = ty; r < 64; r += 4) {
      int sp = sp0 + r;
      int yy = sp >> 5, xx = sp & 31;
      xp[((b * 34 + yy + 1) * 34 + (xx + 1)) * 512 + ci] = f2bf(t[tx][r] * sv);
    }
  } else if (blockIdx.x < 1152) {
    int wid = tid >> 6, lane = tid & 63;
    int co = (blockIdx.x - 1024) * 4 + wid;
    float acc[NB] = {};
    for (int ci = lane; ci < CIN; ci += 64) {
      float wq = wsq[co * CIN + ci];
#pragma unroll
      for (int b = 0; b < NB; ++b) {
        float sv = s[b * CIN + ci];
        acc[b] += wq * sv * sv;
      }
    }
#pragma unroll
    for (int b = 0; b < NB; ++b) {
      float v = acc[b];
      for (int o = 32; o > 0; o >>= 1) v += __shfl_xor(v, o);
      if (lane == 0) demod[b * COUT + co] = rsqrtf(v + 1e-8f);
    }
  } else {
    // zero the 132 border cells (yy or xx in {0,33}) of xp[b]; 4 blocks per b
    int idx = blockIdx.x - 1152;     // 0..31
    int b = idx >> 2, part = idx & 3;
    unsigned* xpu = (unsigned*)xp;
    for (int k = 0; k < 33; ++k) {
      int c = part * 33 + k;
      int yy, xx;
      if (c < 34)       { yy = 0;            xx = c; }
      else if (c < 68)  { yy = 33;           xx = c - 34; }
      else if (c < 100) { yy = 1 + (c - 68); xx = 0; }
      else              { yy = 1 + (c - 100); xx = 33; }
      xpu[((((b * 34 + yy) * 34 + xx) * 512) >> 1) + tid] = 0u;
    }
  }
}

#define MFMA_ROWPAIR(AH, AL, RH, RL)                                              \
  __builtin_amdgcn_s_setprio(1);                                                  \
  acc[RH][0] = __builtin_amdgcn_mfma_f32_16x16x32_bf16(AH, b0, acc[RH][0], 0,0,0);\
  acc[RH][1] = __builtin_amdgcn_mfma_f32_16x16x32_bf16(AH, b1, acc[RH][1], 0,0,0);\
  acc[RH][2] = __builtin_amdgcn_mfma_f32_16x16x32_bf16(AH, b2, acc[RH][2], 0,0,0);\
  acc[RH][3] = __builtin_amdgcn_mfma_f32_16x16x32_bf16(AH, b3, acc[RH][3], 0,0,0);\
  acc[RL][0] = __builtin_amdgcn_mfma_f32_16x16x32_bf16(AL, b0, acc[RL][0], 0,0,0);\
  acc[RL][1] = __builtin_amdgcn_mfma_f32_16x16x32_bf16(AL, b1, acc[RL][1], 0,0,0);\
  acc[RL][2] = __builtin_amdgcn_mfma_f32_16x16x32_bf16(AL, b2, acc[RL][2], 0,0,0);\
  acc[RL][3] = __builtin_amdgcn_mfma_f32_16x16x32_bf16(AL, b3, acc[RL][3], 0,0,0);\
  __builtin_amdgcn_s_setprio(0);

// ---- K5: phase GEMMs, double-buffered pipelined, swizzled LDS, padded bf16 y1 ----
// (R9 structure restored verbatim — measured 64.0 us)
__global__ __launch_bounds__(256, 2) void k_gemm(const short* __restrict__ xp,
                                                 const short* __restrict__ wp,
                                                 short* __restrict__ y1) {
  __shared__ short sW[2][128 * 64];
  __shared__ short sX[2][128 * 64];

  const int tid = threadIdx.x;
  const int wid = tid >> 6, lane = tid & 63;
  const int hi = lane >> 4;
  const int ksw8 = ((tid & 7) ^ ((tid >> 3) & 7)) * 8;
  const int wm = (wid >> 1) * 64, wn = (wid & 1) * 64;

  // block -> job: XCD-grouped (bx%8 = XCD), phases interleaved mod 8
  const int bx = blockIdx.x;
  const int xcd = bx & 7, ii = bx >> 3;
  const int j = (((ii >> 2) << 3) + xcd) * 4 + (ii & 3);
  if (j >= NJOBS) return;

  int ps, base;
  if (j < 276)      { ps = 0; base = 0; }
  else if (j < 540) { ps = 1; base = 276; }
  else if (j < 804) { ps = 2; base = 540; }
  else              { ps = 3; base = 804; }
  const int r = j - base;
  const int nb = r >> 2, mb = r & 3;
  const int psy = ps >> 1, psx = ps & 1;
  const int Ny = 33 - psy, Nx = 33 - psx;
  const int NyNx = Ny * Nx;
  const int N = NB * NyNx;
  const int n0 = nb * 128, m0 = mb * 128;
  const int KT = (2 - psy) * (2 - psx) * 8;  // 32/16/16/8
  const short* wpb = wp + wpoff(ps);

  int bb[4], ay[4], ax[4];
#pragma unroll
  for (int i = 0; i < 4; ++i) {
    int seg = i * 256 + tid;
    int n = n0 + (seg >> 3);
    if (n >= N) n = N - 1;
    int b = n / NyNx;
    int rem = n - b * NyNx;
    int a_y = rem / Nx;
    bb[i] = b; ay[i] = a_y; ax[i] = rem - a_y * Nx;
  }

  auto STAGE = [&](int kt, int d) {
    int tap = kt >> 3, ci0 = (kt & 7) << 6;
    int oy, ox;
    if (ps == 0)      { oy = tap >> 1; ox = tap & 1; }
    else if (ps == 1) { oy = tap;      ox = 1; }
    else if (ps == 2) { oy = 1;        ox = tap; }
    else              { oy = 1;        ox = 1; }
#pragma unroll
    for (int i = 0; i < 4; ++i) {
      int seg = i * 256 + tid;
      const short* gw = wpb + (kt * 512 + m0 + (seg >> 3)) * 64 + ksw8;
      load_lds16(gw, &sW[d][(i * 4 + wid) * 512]);
    }
#pragma unroll
    for (int i = 0; i < 4; ++i) {
      const short* gx = xp + ((bb[i] * 34 + ay[i] + oy) * 34 + ax[i] + ox) * 512 + ci0 + ksw8;
      load_lds16(gx, &sX[d][(i * 4 + wid) * 512]);
    }
  };

  const int c0 = ((hi)     ^ (lane & 7)) * 8;
  const int c1 = ((4 + hi) ^ (lane & 7)) * 8;
  const int rA0 = (wm +  0 + (lane & 15)) * 64, rA1 = (wm + 16 + (lane & 15)) * 64;
  const int rA2 = (wm + 32 + (lane & 15)) * 64, rA3 = (wm + 48 + (lane & 15)) * 64;
  const int rB0 = (wn +  0 + (lane & 15)) * 64, rB1 = (wn + 16 + (lane & 15)) * 64;
  const int rB2 = (wn + 32 + (lane & 15)) * 64, rB3 = (wn + 48 + (lane & 15)) * 64;

  f32x4 acc[4][4] = {};

  STAGE(0, 0);
  STAGE(1, 1);
  __syncthreads();

  int cur = 0;
  for (int t = 0; t < KT; ++t) {
    const short* W = sW[cur];
    const short* X = sX[cur];
    short8 a0, a1, b0, b1, b2, b3;

    a0 = *(const short8*)&W[rA0 + c0];
    a1 = *(const short8*)&W[rA1 + c0];
    b0 = *(const short8*)&X[rB0 + c0];
    b1 = *(const short8*)&X[rB1 + c0];
    b2 = *(const short8*)&X[rB2 + c0];
    b3 = *(const short8*)&X[rB3 + c0];
    MFMA_ROWPAIR(a0, a1, 0, 1);
    __builtin_amdgcn_s_barrier();

    a0 = *(const short8*)&W[rA2 + c0];
    a1 = *(const short8*)&W[rA3 + c0];
    MFMA_ROWPAIR(a0, a1, 2, 3);
    __builtin_amdgcn_s_barrier();

    a0 = *(const short8*)&W[rA0 + c1];
    a1 = *(const short8*)&W[rA1 + c1];
    b0 = *(const short8*)&X[rB0 + c1];
    b1 = *(const short8*)&X[rB1 + c1];
    b2 = *(const short8*)&X[rB2 + c1];
    b3 = *(const short8*)&X[rB3 + c1];
    MFMA_ROWPAIR(a0, a1, 0, 1);
    __builtin_amdgcn_s_barrier();

    a0 = *(const short8*)&W[rA2 + c1];
    a1 = *(const short8*)&W[rA3 + c1];
    MFMA_ROWPAIR(a0, a1, 2, 3);

    __syncthreads();
    if (t + 2 < KT) STAGE(t + 2, cur);
    cur ^= 1;
  }

  // ---- epilogue: f32 acc -> bf16 y1, padded per-(co,b) planes ----
  const int psp = PSPAD(ps);
  const int plb = PLB(ps);
#pragma unroll
  for (int nf = 0; nf < 4; ++nf) {
    int n = n0 + wn + nf * 16 + (lane & 15);
    if (n < N) {
      int b = n / NyNx;
      int rem = n - b * NyNx;
      int nbase = plb + b * psp + rem;
#pragma unroll
      for (int mf = 0; mf < 4; ++mf) {
        int m = m0 + wm + mf * 16 + (lane >> 4) * 4;
#pragma unroll
        for (int rr = 0; rr < 4; ++rr)
          y1[nbase + (m + rr) * 8 * psp] = f2bf(acc[mf][nf][rr]);
      }
    }
  }
}

// ---- K6 v4: half-plane blur blocks with range-restricted loads. ----
__global__ __launch_bounds__(256, 8) void k_blur(const short* __restrict__ y1,
                                                 const float* __restrict__ demod,
                                                 const float* __restrict__ bias,
                                                 float* __restrict__ out) {
  __shared__ float sin_[4][18 * 35];
  __shared__ float stmp[2][18][64];
  const int tid = threadIdx.x;
  const int bc = blockIdx.x & 4095;    // b*512 + co
  const int h = blockIdx.x >> 12;      // row half 0/1
  const int co = bc & 511, b = bc >> 9;
  const int m0v = h * 16;              // first padded-av row needed

  for (int i = tid; i < 4 * 18 * 35; i += 256) ((float*)sin_)[i] = 0.f;
  __syncthreads();

#pragma unroll
  for (int ps = 0; ps < 4; ++ps) {
    const int Nyv = 33 - (ps >> 1), Nxv = 33 - (ps & 1);
    const int total = Nyv * Nxv;
    // element range actually needed: padded rows [m0v, m0v+18) -> av in [m0v-1, m0v+17)
    const int estart = (h == 0) ? 0 : (m0v - 1) * Nxv;   // even: 15*33=495? no ->
    // (m0v-1)*Nxv may be odd; round down to even for pair loads
    const int es = estart & ~1;
    const int eend = min(total, (m0v + 17) * Nxv);
    const short* pl = y1 + PLB(ps) + (co * NB + b) * PSPAD(ps);
    for (int e0 = es + tid * 2; e0 < eend; e0 += 512) {
      unsigned pair = *(const unsigned*)&pl[e0];
      int av0 = e0 / Nxv, ah0 = e0 - av0 * Nxv;
      int lr0 = av0 + 1 - m0v;
      if (lr0 >= 0 && lr0 < 18)
        sin_[ps][lr0 * 35 + ah0 + 1] = bf2f((unsigned short)(pair & 0xffffu));
      int e1 = e0 + 1;
      if (e1 < total) {
        int av1 = e1 / Nxv, ah1 = e1 - av1 * Nxv;
        int lr1 = av1 + 1 - m0v;
        if (lr1 >= 0 && lr1 < 18)
          sin_[ps][lr1 * 35 + ah1 + 1] = bf2f((unsigned short)(pair >> 16));
      }
    }
  }
  __syncthreads();

  const int q = tid & 63;
  const int mx = q >> 1, fx = q & 1;
  int xp0, xi0, xp1, xi1, xp2, xi2, xp3, xi3;
  if (fx) { xp0 = 0; xi0 = mx + 1; xp1 = 1; xi1 = mx + 1; xp2 = 0; xi2 = mx + 2; xp3 = 1; xi3 = mx + 2; }
  else    { xp0 = 1; xi0 = mx;     xp1 = 0; xi1 = mx + 1; xp2 = 1; xi2 = mx + 1; xp3 = 0; xi3 = mx + 2; }

  for (int rt = tid >> 6; rt < 36; rt += 4) {  // rt = pv*18 + local row
    int pv = (rt >= 18) ? 1 : 0;
    int lr = rt - pv * 18;
    if (m0v + lr < 35) {
      float v = 0.25f * sin_[pv * 2 + xp0][lr * 35 + xi0]
              + 0.75f * sin_[pv * 2 + xp1][lr * 35 + xi1]
              + 0.75f * sin_[pv * 2 + xp2][lr * 35 + xi2]
              + 0.25f * sin_[pv * 2 + xp3][lr * 35 + xi3];
      stmp[pv][lr][q] = v;
    } else {
      stmp[pv][lr][q] = 0.f;
    }
  }
  __syncthreads();

  const float dm = demod[b * COUT + co], bs = bias[co];
  for (int pl_ = tid >> 6; pl_ < 32; pl_ += 4) {
    int myl = pl_ >> 1, fy = pl_ & 1;
    float v;
    if (fy) v = 0.25f * stmp[0][myl + 1][q] + 0.75f * stmp[1][myl + 1][q]
              + 0.75f * stmp[0][myl + 2][q] + 0.25f * stmp[1][myl + 2][q];
    else    v = 0.25f * stmp[1][myl][q]     + 0.75f * stmp[0][myl + 1][q]
              + 0.75f * stmp[1][myl + 1][q] + 0.25f * stmp[0][myl + 2][q];
    float val = dm * v + bs;
    int p = h * 32 + pl_;
    out[(bc * 64 + p) * 64 + q] = (val >= 0.f ? val : 0.2f * val) * 1.41421356237309515f;
  }
}

extern "C" void kernel_launch(void* const* d_in, const int* in_sizes, int n_in,
                              void* d_out, int out_size, void* d_ws, size_t ws_size,
                              hipStream_t stream) {
  const float* x      = (const float*)d_in[0];
  const float* style  = (const float*)d_in[1];
  const float* weight = (const float*)d_in[2];
  const float* mod_w  = (const float*)d_in[3];
  const float* mod_b  = (const float*)d_in[4];
  const float* bias   = (const float*)d_in[5];
  float* out = (float*)d_out;
  char* ws = (char*)d_ws;

  float* s     = (float*)(ws + OFF_S);
  float* wsq   = (float*)(ws + OFF_WSQ);
  float* demod = (float*)(ws + OFF_DEMOD);
  short* xp    = (short*)(ws + OFF_XP);
  short* wp    = (short*)(ws + OFF_WP);
  short* y1    = (short*)(ws + OFF_Y1);

  k_prep1<<<1152, 256, 0, stream>>>(style, mod_w, mod_b, s, weight, wp, wsq);
  k_prep2<<<1184, 256, 0, stream>>>(wsq, s, demod, x, xp);
  k_gemm<<<1088, 256, 0, stream>>>(xp, wp, y1);
  k_blur<<<8192, 256, 0, stream>>>(y1, demod, bias, out);
}